// Round 2
// baseline (2968.546 us; speedup 1.0000x reference)
//
#include <hip/hip_runtime.h>
#include <hip/hip_bf16.h>
#include <hip/hip_cooperative_groups.h>

namespace cg = cooperative_groups;

// ---------------- types ----------------
typedef __bf16 bf16x8 __attribute__((ext_vector_type(8)));
typedef float  f32x4  __attribute__((ext_vector_type(4)));
typedef unsigned short u16x8 __attribute__((ext_vector_type(8)));

#define NTOK 16384      // B*S
#define SEQ  4096
#define DIM  128
#define NSEG 13         // 1 g-segment + 12 f-segments
#define NM   12
#define NK   13

// round-to-nearest-even f32 -> bf16 bits
__device__ inline unsigned short f2bf(float f) {
    unsigned int u = __float_as_uint(f);
    unsigned int r = (u + 0x7FFFu + ((u >> 16) & 1u)) >> 16;
    return (unsigned short)r;
}
__device__ inline float bf2f(unsigned short h) {
    return __uint_as_float(((unsigned int)h) << 16);
}
// packed f32x2 -> bf16x2 (lo=a, hi=b)
__device__ inline unsigned int cvtpk(float a, float b) {
    unsigned int r;
    asm("v_cvt_pk_bf16_f32 %0, %1, %2" : "=v"(r) : "v"(a), "v"(b));
    return r;
}

// 5-op gelu, CORRECT small-|u| form (leading correction is QUADRATIC):
//   gelu(u) = 0.5u + u^2*(c0 + u^2*c1 + u^4*c2),  c0=0.5*sqrt(2/pi), c1=-c0/6, c2=c0/40
__device__ inline float gelu_f(float u) {
    const float c0 = 0.3989422804f;
    const float c1 = -0.0664903801f;
    const float c2 = 0.0099735570f;
    float u2 = u * u;
    float p  = __builtin_fmaf(u2, c2, c1);
    p        = __builtin_fmaf(u2, p, c0);
    return __builtin_fmaf(u2, p, 0.5f * u);
}

// LDS XOR-swizzle: rows are 256B (128 u16). XOR byte bits [4:6] with row bits [8:10].
__device__ inline int swz(int u16idx) {
    int byte = u16idx << 1;
    byte ^= ((byte >> 8) & 7) << 4;
    return byte >> 1;
}

// ---------------- kernel 1: fused embed (x = emb[data]+apc -> bf16) + weight conv ----------------
#define EMB_BLOCKS 8192                         // 2 rows per 256-thread block
#define CONV_BLOCKS ((NSEG * DIM * DIM + 255) / 256)
__global__ __launch_bounds__(256) void prep_kernel(
    const int* __restrict__ data, const float* __restrict__ emb,
    const float* __restrict__ apc, unsigned short* __restrict__ xb,
    const float* __restrict__ g_W1, const float* __restrict__ g_W2,
    const float* __restrict__ f_W1, const float* __restrict__ f_W2,
    unsigned short* __restrict__ wb1T, unsigned short* __restrict__ wb2Tg,
    unsigned short* __restrict__ wb2Tf)
{
    int tid = threadIdx.x;
    if (blockIdx.x < EMB_BLOCKS) {
        int n = blockIdx.x * 2 + (tid >> 7);
        int d = tid & 127;
        int s = n & (SEQ - 1);
        int tok = data[n];
        float v = emb[(size_t)tok * DIM + d] + apc[s * DIM + d];
        xb[(size_t)n * DIM + d] = f2bf(v);
    } else {
        int i = (blockIdx.x - EMB_BLOCKS) * 256 + tid;
        if (i < NSEG * DIM * DIM) {
            int seg = i >> 14;
            int e = (i >> 7) & 127;
            int d = i & 127;
            float v = (seg == 0) ? g_W1[d * DIM + e]
                                 : f_W1[((seg - 1) * DIM + d) * DIM + e];
            wb1T[i] = f2bf(v);
        }
        if (i < DIM * DIM) {
            int c = i >> 7, e = i & 127;
            wb2Tg[i] = f2bf(g_W2[e * DIM + c]);
        }
        if (i < NM * 16 * DIM) {
            int m = i >> 11;
            int c = (i >> 7) & 15;
            int e = i & 127;
            float v = (c < NK) ? f_W2[(m * DIM + e) * NK + c] : 0.f;
            wb2Tf[i] = f2bf(v);
        }
    }
}

// ---------------- kernel 2: fused MLP — W in LDS (reused 32x), X direct from global ----------------
__global__ __launch_bounds__(256, 3) void mlp_kernel(
    const unsigned short* __restrict__ xb,
    const unsigned short* __restrict__ wb1T,
    const unsigned short* __restrict__ wb2Tg,
    const unsigned short* __restrict__ wb2Tf,
    const float* __restrict__ g_b1, const float* __restrict__ g_b2,
    const float* __restrict__ f_b1, const float* __restrict__ f_b2,
    float* __restrict__ resF, unsigned short* __restrict__ resB,
    unsigned short* __restrict__ Wallb)
{
    const int seg  = blockIdx.y;           // 0 => g ; 1..12 => f[seg-1]
    const int row0 = blockIdx.x * 64;
    const int tid  = threadIdx.x;
    const int wave = tid >> 6;             // 0..3
    const int lane = tid & 63;

    __shared__ __align__(16) unsigned short Hs[4][16 * DIM];  // 16 KB wave-private strips
    __shared__ __align__(16) unsigned short W1s[DIM * DIM];   // 32 KB
    __shared__ __align__(16) unsigned short W2fs[16 * DIM];   // 4 KB

    const int r16   = lane & 15;
    const int kgrp  = (lane >> 4) * 8;
    const int crow0 = (lane >> 4) << 2;    // strip-local C row base

    // biases into registers (overlaps staging)
    const float* b1p = (seg == 0) ? g_b1 : (f_b1 + (seg - 1) * DIM);
    float bias1[8];
    #pragma unroll
    for (int t = 0; t < 8; ++t) bias1[t] = b1p[t * 16 + r16];
    float bias2[8];
    float bias2f = 0.f;
    if (seg == 0) {
        #pragma unroll
        for (int t = 0; t < 8; ++t) bias2[t] = g_b2[t * 16 + r16];
    } else {
        bias2f = (r16 < NK) ? f_b2[(seg - 1) * NK + r16] : 0.f;
    }

    // stage W1T (128x128) swizzled
    {
        const int4* wg = reinterpret_cast<const int4*>(wb1T + (size_t)seg * DIM * DIM);
        #pragma unroll
        for (int i = 0; i < 8; ++i)
            *reinterpret_cast<int4*>(&W1s[swz((tid + i * 256) * 8)]) = wg[tid + i * 256];
    }
    // stage W2f (16x128) swizzled — f-segments only
    if (seg != 0) {
        const int4* wg = reinterpret_cast<const int4*>(wb2Tf + (size_t)(seg - 1) * 16 * DIM);
        *reinterpret_cast<int4*>(&W2fs[swz(tid * 8)]) = wg[tid];
    }
    __syncthreads();   // the ONLY barrier (waits on W staging only)

    // ---- layer 1: acc = X @ W1 ; A direct from global, B from LDS ----
    const unsigned short* xrow = xb + (size_t)(row0 + wave * 16 + r16) * DIM + kgrp;
    f32x4 acc[8];
    #pragma unroll
    for (int t = 0; t < 8; ++t) acc[t] = (f32x4){0.f, 0.f, 0.f, 0.f};
    #pragma unroll
    for (int kk = 0; kk < 4; ++kk) {
        bf16x8 a = *reinterpret_cast<const bf16x8*>(xrow + kk * 32);
        #pragma unroll
        for (int t = 0; t < 8; ++t) {
            bf16x8 b = *reinterpret_cast<const bf16x8*>(&W1s[swz((t * 16 + r16) * DIM + kk * 32 + kgrp)]);
            acc[t] = __builtin_amdgcn_mfma_f32_16x16x32_bf16(a, b, acc[t], 0, 0, 0);
        }
    }

    // ---- gelu -> H into this wave's own swizzled strip (cvt_pk pairs) ----
    unsigned short* hs = Hs[wave];
    #pragma unroll
    for (int t = 0; t < 8; ++t) {
        int col = t * 16 + r16;
        #pragma unroll
        for (int r = 0; r < 4; r += 2) {
            float g0 = gelu_f(acc[t][r]     + bias1[t]);
            float g1 = gelu_f(acc[t][r + 1] + bias1[t]);
            unsigned int pk = cvtpk(g0, g1);
            hs[swz((crow0 + r)     * DIM + col)] = (unsigned short)pk;
            hs[swz((crow0 + r + 1) * DIM + col)] = (unsigned short)(pk >> 16);
        }
    }

    // ---- layer 2 ----
    if (seg == 0) {
        f32x4 acc2[8];
        #pragma unroll
        for (int t = 0; t < 8; ++t) acc2[t] = (f32x4){0.f, 0.f, 0.f, 0.f};
        #pragma unroll
        for (int kk = 0; kk < 4; ++kk) {
            bf16x8 a = *reinterpret_cast<const bf16x8*>(&hs[swz(r16 * DIM + kk * 32 + kgrp)]);
            #pragma unroll
            for (int t = 0; t < 8; ++t) {
                bf16x8 b = *reinterpret_cast<const bf16x8*>(wb2Tg + (size_t)(t * 16 + r16) * DIM + kk * 32 + kgrp);
                acc2[t] = __builtin_amdgcn_mfma_f32_16x16x32_bf16(a, b, acc2[t], 0, 0, 0);
            }
        }
        #pragma unroll
        for (int t = 0; t < 8; ++t) {
            int col = t * 16 + r16;
            #pragma unroll
            for (int r = 0; r < 4; r += 2) {
                int grow = row0 + wave * 16 + crow0 + r;
                float v0 = acc2[t][r]     + bias2[t];
                float v1 = acc2[t][r + 1] + bias2[t];
                resF[(size_t)grow * DIM + col]       = v0;
                resF[(size_t)(grow + 1) * DIM + col] = v1;
                unsigned int pk = cvtpk(v0, v1);
                resB[(size_t)grow * DIM + col]       = (unsigned short)pk;
                resB[(size_t)(grow + 1) * DIM + col] = (unsigned short)(pk >> 16);
            }
        }
    } else {
        int m = seg - 1;
        f32x4 acc2 = (f32x4){0.f, 0.f, 0.f, 0.f};
        #pragma unroll
        for (int kk = 0; kk < 4; ++kk) {
            bf16x8 a = *reinterpret_cast<const bf16x8*>(&hs[swz(r16 * DIM + kk * 32 + kgrp)]);
            bf16x8 b = *reinterpret_cast<const bf16x8*>(&W2fs[swz(r16 * DIM + kk * 32 + kgrp)]);
            acc2 = __builtin_amdgcn_mfma_f32_16x16x32_bf16(a, b, acc2, 0, 0, 0);
        }
        #pragma unroll
        for (int r = 0; r < 4; r += 2) {
            int grow = row0 + wave * 16 + crow0 + r;
            unsigned int pk = cvtpk(acc2[r] + bias2f, acc2[r + 1] + bias2f);
            Wallb[((size_t)m * NTOK + grow) * 16 + r16]     = (unsigned short)pk;
            Wallb[((size_t)m * NTOK + grow + 1) * 16 + r16] = (unsigned short)(pk >> 16);
        }
    }
}

// ---------------- kernel 3a: one chord-scan step (fallback path, proven) ----------------
template<int FINAL>
__global__ __launch_bounds__(256) void scan_kernel(
    const unsigned short* __restrict__ Vb,
    const unsigned short* __restrict__ resB, const float* __restrict__ resF,
    const unsigned short* __restrict__ Wmb,
    unsigned short* __restrict__ VoutB, float* __restrict__ outF)
{
    const int bid   = (int)blockIdx.x;
    const int xcd   = bid & 7;
    const int bb    = xcd >> 1;                          // batch 0..3
    const int local = ((bid >> 3) << 1) | (xcd & 1);     // 0..255 within batch
    const int tid   = threadIdx.x;
    const int n     = ((bb << 8) + local) * 16 + (tid >> 4);
    const int sub   = tid & 15;
    const int s     = n & (SEQ - 1);
    const int lanebase = (tid & 63) & ~15;

    float wv = bf2f(Wmb[(size_t)n * 16 + sub]);

    float out[8];
    if (FINAL) {
        const f32x4* rf = reinterpret_cast<const f32x4*>(resF + (size_t)n * DIM + sub * 8);
        f32x4 r0 = rf[0], r1 = rf[1];
        #pragma unroll
        for (int j = 0; j < 4; ++j) { out[j] = r0[j]; out[4 + j] = r1[j]; }
    } else {
        u16x8 r = *reinterpret_cast<const u16x8*>(resB + (size_t)n * DIM + sub * 8);
        #pragma unroll
        for (int j = 0; j < 8; ++j) out[j] = bf2f(r[j]);
    }

    const size_t vbase = (size_t)(bb << 12) * DIM;
    #pragma unroll
    for (int k = 0; k < NK; ++k) {
        float w = __shfl(wv, lanebase + k, 64);
        int   c = (s + ((k == 0) ? 0 : (1 << (k - 1)))) & (SEQ - 1);
        u16x8 v = *reinterpret_cast<const u16x8*>(Vb + vbase + (size_t)c * DIM + sub * 8);
        #pragma unroll
        for (int j = 0; j < 8; ++j) out[j] += w * bf2f(v[j]);
    }

    if (FINAL) {
        f32x4 o0, o1;
        #pragma unroll
        for (int j = 0; j < 4; ++j) { o0[j] = out[j]; o1[j] = out[4 + j]; }
        f32x4* og = reinterpret_cast<f32x4*>(outF + (size_t)n * DIM + sub * 8);
        og[0] = o0; og[1] = o1;
    } else {
        u16x8 o;
        #pragma unroll
        for (int j = 0; j < 8; ++j) o[j] = f2bf(out[j]);
        *reinterpret_cast<u16x8*>(VoutB + (size_t)n * DIM + sub * 8) = o;
    }
}

// ---------------- kernel 3b: ALL 12 steps, persistent cooperative ----------------
// Numerics IDENTICAL to the 12-launch path: steps 0..10 add bf16 res (resBv),
// final step adds f32 resF. Explicit agent-scope fences around grid.sync()
// guard cross-XCD L2 visibility.
__global__ __launch_bounds__(256, 4) void scan_all_kernel(
    const unsigned short* __restrict__ resB,   // V0 (bf16 of res)
    const float* __restrict__ resF,            // res (f32, final step only)
    const unsigned short* __restrict__ Wallb,  // [NM][NTOK][16]
    unsigned short* __restrict__ VbA,
    unsigned short* __restrict__ VbB,
    float* __restrict__ outF)
{
    const int bid   = (int)blockIdx.x;
    const int xcd   = bid & 7;
    const int bb    = xcd >> 1;                          // batch 0..3
    const int local = ((bid >> 3) << 1) | (xcd & 1);     // 0..255 within batch
    const int tid   = threadIdx.x;
    const int n     = ((bb << 8) + local) * 16 + (tid >> 4);
    const int sub   = tid & 15;
    const int s     = n & (SEQ - 1);
    const int lanebase = (tid & 63) & ~15;

    cg::grid_group grid = cg::this_grid();

    // ---- one-time loads: bf16 res (steps 0..10), step-weights, gather offsets ----
    float resBv[8];
    {
        u16x8 r = *reinterpret_cast<const u16x8*>(resB + (size_t)n * DIM + sub * 8);
        #pragma unroll
        for (int j = 0; j < 8; ++j) resBv[j] = bf2f(r[j]);
    }
    float wv[NM];
    #pragma unroll
    for (int m = 0; m < NM; ++m)
        wv[m] = bf2f(Wallb[((size_t)m * NTOK + n) * 16 + sub]);

    int off[NK];   // element offset within the batch slice (includes sub*8)
    #pragma unroll
    for (int k = 0; k < NK; ++k) {
        int c = (s + ((k == 0) ? 0 : (1 << (k - 1)))) & (SEQ - 1);
        off[k] = c * DIM + sub * 8;
    }
    const size_t vbase = (size_t)(bb << 12) * DIM;
    const size_t wslot = (size_t)n * DIM + sub * 8;

    // ---- 12 scan steps, grid-synced ----
    #pragma unroll
    for (int m = 0; m < NM; ++m) {
        const unsigned short* vin =
            (m == 0) ? resB : (((m - 1) & 1) ? VbB : VbA);

        float out[8];
        if (m == NM - 1) {
            const f32x4* rf = reinterpret_cast<const f32x4*>(resF + wslot);
            f32x4 r0 = rf[0], r1 = rf[1];
            #pragma unroll
            for (int j = 0; j < 4; ++j) { out[j] = r0[j]; out[4 + j] = r1[j]; }
        } else {
            #pragma unroll
            for (int j = 0; j < 8; ++j) out[j] = resBv[j];
        }

        #pragma unroll
        for (int k = 0; k < NK; ++k) {
            float w = __shfl(wv[m], lanebase + k, 64);
            u16x8 v = *reinterpret_cast<const u16x8*>(vin + vbase + (size_t)off[k]);
            #pragma unroll
            for (int j = 0; j < 8; ++j) out[j] += w * bf2f(v[j]);
        }

        if (m == NM - 1) {
            f32x4 o0, o1;
            #pragma unroll
            for (int j = 0; j < 4; ++j) { o0[j] = out[j]; o1[j] = out[4 + j]; }
            f32x4* og = reinterpret_cast<f32x4*>(outF + wslot);
            og[0] = o0; og[1] = o1;
        } else {
            unsigned short* vout = (m & 1) ? VbB : VbA;
            u16x8 o;
            #pragma unroll
            for (int j = 0; j < 8; ++j) o[j] = f2bf(out[j]);
            *reinterpret_cast<u16x8*>(vout + wslot) = o;
            __threadfence();   // release: drain stores to device scope (cross-XCD)
            grid.sync();
            __threadfence();   // acquire: no stale L2 lines on the read side
        }
    }
}

// ---------------- launch ----------------
extern "C" void kernel_launch(void* const* d_in, const int* in_sizes, int n_in,
                              void* d_out, int out_size, void* d_ws, size_t ws_size,
                              hipStream_t stream) {
    const int*   data = (const int*)  d_in[0];
    const float* emb  = (const float*)d_in[2];
    const float* apc  = (const float*)d_in[3];
    const float* g_W1 = (const float*)d_in[4];
    const float* g_b1 = (const float*)d_in[5];
    const float* g_W2 = (const float*)d_in[6];
    const float* g_b2 = (const float*)d_in[7];
    const float* f_W1 = (const float*)d_in[8];
    const float* f_b1 = (const float*)d_in[9];
    const float* f_W2 = (const float*)d_in[10];
    const float* f_b2 = (const float*)d_in[11];
    float* out = (float*)d_out;

    char* ws = (char*)d_ws;
    size_t off = 0;
    auto alloc = [&](size_t bytes) {
        void* p = ws + off;
        off += (bytes + 255) & ~(size_t)255;
        return p;
    };
    unsigned short* xb    = (unsigned short*)alloc((size_t)NTOK * DIM * 2);
    unsigned short* wb1T  = (unsigned short*)alloc((size_t)NSEG * DIM * DIM * 2);
    unsigned short* wb2Tg = (unsigned short*)alloc((size_t)DIM * DIM * 2);
    unsigned short* wb2Tf = (unsigned short*)alloc((size_t)NM * 16 * DIM * 2);
    float*          resF  = (float*)alloc((size_t)NTOK * DIM * 4);
    unsigned short* resB  = (unsigned short*)alloc((size_t)NTOK * DIM * 2);
    unsigned short* VbA   = (unsigned short*)alloc((size_t)NTOK * DIM * 2);
    unsigned short* VbB   = (unsigned short*)alloc((size_t)NTOK * DIM * 2);
    unsigned short* Wallb = (unsigned short*)alloc((size_t)NM * NTOK * 16 * 2);
    (void)ws_size; (void)in_sizes; (void)n_in; (void)out_size;

    prep_kernel<<<EMB_BLOCKS + CONV_BLOCKS, 256, 0, stream>>>(
        data, emb, apc, xb, g_W1, g_W2, f_W1, f_W2, wb1T, wb2Tg, wb2Tf);

    dim3 grid(NTOK / 64, NSEG);
    mlp_kernel<<<grid, 256, 0, stream>>>(xb, wb1T, wb2Tg, wb2Tf,
                                         g_b1, g_b2, f_b1, f_b2, resF, resB, Wallb);

    // Try: one cooperative kernel runs all 12 scan steps with grid.sync().
    // If the runtime rejects the cooperative launch, fall back to 12 launches.
    hipError_t coop_err;
    {
        const unsigned short* a_resB  = resB;
        const float*          a_resF  = resF;
        const unsigned short* a_Wallb = Wallb;
        unsigned short*       a_VbA   = VbA;
        unsigned short*       a_VbB   = VbB;
        float*                a_out   = out;
        void* kargs[] = { (void*)&a_resB, (void*)&a_resF, (void*)&a_Wallb,
                          (void*)&a_VbA, (void*)&a_VbB, (void*)&a_out };
        coop_err = hipLaunchCooperativeKernel((const void*)scan_all_kernel,
                                              dim3(1024), dim3(256), kargs, 0, stream);
    }
    if (coop_err != hipSuccess) {
        const unsigned short* vin = resB;
        for (int m = 0; m < NM; ++m) {
            const unsigned short* Wm = Wallb + (size_t)m * NTOK * 16;
            if (m == NM - 1) {
                scan_kernel<1><<<NTOK / 16, 256, 0, stream>>>(
                    vin, resB, resF, Wm, nullptr, out);
            } else {
                unsigned short* vout = (m & 1) ? VbB : VbA;
                scan_kernel<0><<<NTOK / 16, 256, 0, stream>>>(
                    vin, resB, resF, Wm, vout, nullptr);
                vin = vout;
            }
        }
    }
}

// Round 3
// 97.379 us; speedup vs baseline: 30.4844x; 30.4844x over previous
//
#include <hip/hip_runtime.h>
#include <hip/hip_bf16.h>

// ---------------- types ----------------
typedef __bf16 bf16x8 __attribute__((ext_vector_type(8)));
typedef float  f32x4  __attribute__((ext_vector_type(4)));
typedef unsigned short u16x8 __attribute__((ext_vector_type(8)));

#define NTOK 16384      // B*S
#define SEQ  4096
#define DIM  128
#define NSEG 13         // 1 g-segment + 12 f-segments
#define NM   12
#define NK   13

// round-to-nearest-even f32 -> bf16 bits
__device__ inline unsigned short f2bf(float f) {
    unsigned int u = __float_as_uint(f);
    unsigned int r = (u + 0x7FFFu + ((u >> 16) & 1u)) >> 16;
    return (unsigned short)r;
}
__device__ inline float bf2f(unsigned short h) {
    return __uint_as_float(((unsigned int)h) << 16);
}
// packed f32x2 -> bf16x2 (lo=a, hi=b), RNE (same as f2bf)
__device__ inline unsigned int cvtpk(float a, float b) {
    unsigned int r;
    asm("v_cvt_pk_bf16_f32 %0, %1, %2" : "=v"(r) : "v"(a), "v"(b));
    return r;
}

// 5-op gelu, CORRECT small-|u| form (leading correction is QUADRATIC):
//   gelu(u) = 0.5u + u^2*(c0 + u^2*c1 + u^4*c2),  c0=0.5*sqrt(2/pi), c1=-c0/6, c2=c0/40
__device__ inline float gelu_f(float u) {
    const float c0 = 0.3989422804f;
    const float c1 = -0.0664903801f;
    const float c2 = 0.0099735570f;
    float u2 = u * u;
    float p  = __builtin_fmaf(u2, c2, c1);
    p        = __builtin_fmaf(u2, p, c0);
    return __builtin_fmaf(u2, p, 0.5f * u);
}

// LDS XOR-swizzle: rows are 256B (128 u16). XOR byte bits [4:6] with row bits [8:10].
__device__ inline int swz(int u16idx) {
    int byte = u16idx << 1;
    byte ^= ((byte >> 8) & 7) << 4;
    return byte >> 1;
}

// ---------------- kernel 1: fused embed (x = emb[data]+apc -> bf16) + weight conv ----------------
#define EMB_BLOCKS 8192                         // 2 rows per 256-thread block
#define CONV_BLOCKS ((NSEG * DIM * DIM + 255) / 256)
__global__ __launch_bounds__(256) void prep_kernel(
    const int* __restrict__ data, const float* __restrict__ emb,
    const float* __restrict__ apc, unsigned short* __restrict__ xb,
    const float* __restrict__ g_W1, const float* __restrict__ g_W2,
    const float* __restrict__ f_W1, const float* __restrict__ f_W2,
    unsigned short* __restrict__ wb1T, unsigned short* __restrict__ wb2Tg,
    unsigned short* __restrict__ wb2Tf)
{
    int tid = threadIdx.x;
    if (blockIdx.x < EMB_BLOCKS) {
        int n = blockIdx.x * 2 + (tid >> 7);
        int d = tid & 127;
        int s = n & (SEQ - 1);
        int tok = data[n];
        float v = emb[(size_t)tok * DIM + d] + apc[s * DIM + d];
        xb[(size_t)n * DIM + d] = f2bf(v);
    } else {
        int i = (blockIdx.x - EMB_BLOCKS) * 256 + tid;
        if (i < NSEG * DIM * DIM) {
            int seg = i >> 14;
            int e = (i >> 7) & 127;
            int d = i & 127;
            float v = (seg == 0) ? g_W1[d * DIM + e]
                                 : f_W1[((seg - 1) * DIM + d) * DIM + e];
            wb1T[i] = f2bf(v);
        }
        if (i < DIM * DIM) {
            int c = i >> 7, e = i & 127;
            wb2Tg[i] = f2bf(g_W2[e * DIM + c]);
        }
        if (i < NM * 16 * DIM) {
            int m = i >> 11;
            int c = (i >> 7) & 15;
            int e = i & 127;
            float v = (c < NK) ? f_W2[(m * DIM + e) * NK + c] : 0.f;
            wb2Tf[i] = f2bf(v);
        }
    }
}

// ---------------- kernel 2: fused MLP — W in LDS (reused 32x), X direct from global ----------------
__global__ __launch_bounds__(256, 3) void mlp_kernel(
    const unsigned short* __restrict__ xb,
    const unsigned short* __restrict__ wb1T,
    const unsigned short* __restrict__ wb2Tg,
    const unsigned short* __restrict__ wb2Tf,
    const float* __restrict__ g_b1, const float* __restrict__ g_b2,
    const float* __restrict__ f_b1, const float* __restrict__ f_b2,
    float* __restrict__ resF, unsigned short* __restrict__ resB,
    unsigned short* __restrict__ Wallb)
{
    const int seg  = blockIdx.y;           // 0 => g ; 1..12 => f[seg-1]
    const int row0 = blockIdx.x * 64;
    const int tid  = threadIdx.x;
    const int wave = tid >> 6;             // 0..3
    const int lane = tid & 63;

    __shared__ __align__(16) unsigned short Hs[4][16 * DIM];  // 16 KB wave-private strips
    __shared__ __align__(16) unsigned short W1s[DIM * DIM];   // 32 KB
    __shared__ __align__(16) unsigned short W2fs[16 * DIM];   // 4 KB

    const int r16   = lane & 15;
    const int kgrp  = (lane >> 4) * 8;
    const int crow0 = (lane >> 4) << 2;    // strip-local C row base

    // biases into registers (overlaps staging)
    const float* b1p = (seg == 0) ? g_b1 : (f_b1 + (seg - 1) * DIM);
    float bias1[8];
    #pragma unroll
    for (int t = 0; t < 8; ++t) bias1[t] = b1p[t * 16 + r16];
    float bias2[8];
    float bias2f = 0.f;
    if (seg == 0) {
        #pragma unroll
        for (int t = 0; t < 8; ++t) bias2[t] = g_b2[t * 16 + r16];
    } else {
        bias2f = (r16 < NK) ? f_b2[(seg - 1) * NK + r16] : 0.f;
    }

    // stage W1T (128x128) swizzled
    {
        const int4* wg = reinterpret_cast<const int4*>(wb1T + (size_t)seg * DIM * DIM);
        #pragma unroll
        for (int i = 0; i < 8; ++i)
            *reinterpret_cast<int4*>(&W1s[swz((tid + i * 256) * 8)]) = wg[tid + i * 256];
    }
    // stage W2f (16x128) swizzled — f-segments only
    if (seg != 0) {
        const int4* wg = reinterpret_cast<const int4*>(wb2Tf + (size_t)(seg - 1) * 16 * DIM);
        *reinterpret_cast<int4*>(&W2fs[swz(tid * 8)]) = wg[tid];
    }
    __syncthreads();   // the ONLY barrier (waits on W staging only)

    // ---- layer 1: acc = X @ W1 ; A direct from global, B from LDS ----
    const unsigned short* xrow = xb + (size_t)(row0 + wave * 16 + r16) * DIM + kgrp;
    f32x4 acc[8];
    #pragma unroll
    for (int t = 0; t < 8; ++t) acc[t] = (f32x4){0.f, 0.f, 0.f, 0.f};
    #pragma unroll
    for (int kk = 0; kk < 4; ++kk) {
        bf16x8 a = *reinterpret_cast<const bf16x8*>(xrow + kk * 32);
        #pragma unroll
        for (int t = 0; t < 8; ++t) {
            bf16x8 b = *reinterpret_cast<const bf16x8*>(&W1s[swz((t * 16 + r16) * DIM + kk * 32 + kgrp)]);
            acc[t] = __builtin_amdgcn_mfma_f32_16x16x32_bf16(a, b, acc[t], 0, 0, 0);
        }
    }

    // ---- gelu -> H into this wave's own swizzled strip (cvt_pk pairs) ----
    unsigned short* hs = Hs[wave];
    #pragma unroll
    for (int t = 0; t < 8; ++t) {
        int col = t * 16 + r16;
        #pragma unroll
        for (int r = 0; r < 4; r += 2) {
            float g0 = gelu_f(acc[t][r]     + bias1[t]);
            float g1 = gelu_f(acc[t][r + 1] + bias1[t]);
            unsigned int pk = cvtpk(g0, g1);
            hs[swz((crow0 + r)     * DIM + col)] = (unsigned short)pk;
            hs[swz((crow0 + r + 1) * DIM + col)] = (unsigned short)(pk >> 16);
        }
    }

    // ---- layer 2 ----
    if (seg == 0) {
        f32x4 acc2[8];
        #pragma unroll
        for (int t = 0; t < 8; ++t) acc2[t] = (f32x4){0.f, 0.f, 0.f, 0.f};
        #pragma unroll
        for (int kk = 0; kk < 4; ++kk) {
            bf16x8 a = *reinterpret_cast<const bf16x8*>(&hs[swz(r16 * DIM + kk * 32 + kgrp)]);
            #pragma unroll
            for (int t = 0; t < 8; ++t) {
                bf16x8 b = *reinterpret_cast<const bf16x8*>(wb2Tg + (size_t)(t * 16 + r16) * DIM + kk * 32 + kgrp);
                acc2[t] = __builtin_amdgcn_mfma_f32_16x16x32_bf16(a, b, acc2[t], 0, 0, 0);
            }
        }
        #pragma unroll
        for (int t = 0; t < 8; ++t) {
            int col = t * 16 + r16;
            #pragma unroll
            for (int r = 0; r < 4; r += 2) {
                int grow = row0 + wave * 16 + crow0 + r;
                float v0 = acc2[t][r]     + bias2[t];
                float v1 = acc2[t][r + 1] + bias2[t];
                resF[(size_t)grow * DIM + col]       = v0;
                resF[(size_t)(grow + 1) * DIM + col] = v1;
                unsigned int pk = cvtpk(v0, v1);
                resB[(size_t)grow * DIM + col]       = (unsigned short)pk;
                resB[(size_t)(grow + 1) * DIM + col] = (unsigned short)(pk >> 16);
            }
        }
    } else {
        int m = seg - 1;
        f32x4 acc2 = (f32x4){0.f, 0.f, 0.f, 0.f};
        #pragma unroll
        for (int kk = 0; kk < 4; ++kk) {
            bf16x8 a = *reinterpret_cast<const bf16x8*>(&hs[swz(r16 * DIM + kk * 32 + kgrp)]);
            bf16x8 b = *reinterpret_cast<const bf16x8*>(&W2fs[swz(r16 * DIM + kk * 32 + kgrp)]);
            acc2 = __builtin_amdgcn_mfma_f32_16x16x32_bf16(a, b, acc2, 0, 0, 0);
        }
        #pragma unroll
        for (int r = 0; r < 4; r += 2) {
            int grow = row0 + wave * 16 + crow0 + r;
            unsigned int pk = cvtpk(acc2[r] + bias2f, acc2[r + 1] + bias2f);
            Wallb[((size_t)m * NTOK + grow) * 16 + r16]     = (unsigned short)pk;
            Wallb[((size_t)m * NTOK + grow + 1) * 16 + r16] = (unsigned short)(pk >> 16);
        }
    }
}

// ---------------- kernel 3: ALL 12 scan steps, V channel-slice resident in LDS ----------------
// Block = (batch, 4-channel chunk): V slice = 4096 tok x 4 ch bf16 = 32 KB, double-buffered
// in LDS (64 KB). 1024 threads, 4 tokens/thread (t = j*1024 + tid -> lane-consecutive tokens:
// coalesced W loads, uniform LDS bank phases). One __syncthreads per step. res in registers.
// Numerics identical to the 12-launch path: bf16 V carry (RNE), bf16 res steps 0..10,
// f32 resF + f32 out at step 11, same k-order FMA chain.
#define CCH 4
#define VBYTES (SEQ * CCH * 2)      // 32 KB per buffer
__global__ __launch_bounds__(1024) void scan_lds_kernel(
    const unsigned short* __restrict__ resB,
    const float* __restrict__ resF,
    const unsigned short* __restrict__ Wallb,   // [NM][NTOK][16]
    float* __restrict__ outF)
{
    __shared__ __align__(16) unsigned short Vs[2][SEQ * CCH];   // 2 x 32 KB

    const int bb  = blockIdx.x >> 5;           // batch 0..3
    const int d0  = (blockIdx.x & 31) * CCH;   // channel chunk
    const int tid = threadIdx.x;               // 0..1023

    // ---- one-time: load res (bf16 values, as the old path), seed V0 in LDS ----
    float res0[4], res1[4], res2[4], res3[4];  // res[j][c], j = token slot
    #pragma unroll
    for (int j = 0; j < 4; ++j) {
        int t = j * 1024 + tid;
        int n = (bb << 12) + t;
        uint2 r = *reinterpret_cast<const uint2*>(resB + (size_t)n * DIM + d0);
        float* rr = (j == 0) ? res0 : (j == 1) ? res1 : (j == 2) ? res2 : res3;
        rr[0] = __uint_as_float(r.x << 16);
        rr[1] = __uint_as_float(r.x & 0xffff0000u);
        rr[2] = __uint_as_float(r.y << 16);
        rr[3] = __uint_as_float(r.y & 0xffff0000u);
        *reinterpret_cast<uint2*>(&Vs[0][t * CCH]) = r;
    }
    __syncthreads();

    const unsigned short* wbase = Wallb + ((size_t)(bb << 12)) * 16;

    unsigned int cur = 0;
    #pragma unroll 1
    for (int m = 0; m < NM - 1; ++m) {         // steps 0..10: bf16 V carry in LDS
        const unsigned short* wp = wbase + (size_t)m * NTOK * 16;
        const char* rd = (const char*)&Vs[cur][0];
        unsigned short* wr = &Vs[cur ^ 1][0];

        #pragma unroll
        for (int j = 0; j < 4; ++j) {
            int t = j * 1024 + tid;
            unsigned int t8 = (unsigned int)t * 8u;
            uint4 w0 = *reinterpret_cast<const uint4*>(wp + (size_t)t * 16);
            uint4 w1 = *reinterpret_cast<const uint4*>(wp + (size_t)t * 16 + 8);
            const float* rr = (j == 0) ? res0 : (j == 1) ? res1 : (j == 2) ? res2 : res3;
            float o0 = rr[0], o1 = rr[1], o2 = rr[2], o3 = rr[3];

            #pragma unroll
            for (int k = 0; k < NK; ++k) {
                const int off = (k == 0) ? 0 : (1 << (k - 1));
                unsigned int ww =
                    (k < 2) ? w0.x : (k < 4) ? w0.y : (k < 6) ? w0.z : (k < 8) ? w0.w :
                    (k < 10) ? w1.x : (k < 12) ? w1.y : w1.z;
                float w = (k & 1) ? __uint_as_float(ww & 0xffff0000u)
                                  : __uint_as_float(ww << 16);
                unsigned int a = (t8 + (unsigned int)off * 8u) & (unsigned int)(VBYTES - 1);
                uint2 v = *reinterpret_cast<const uint2*>(rd + a);
                o0 = __builtin_fmaf(w, __uint_as_float(v.x << 16),          o0);
                o1 = __builtin_fmaf(w, __uint_as_float(v.x & 0xffff0000u), o1);
                o2 = __builtin_fmaf(w, __uint_as_float(v.y << 16),          o2);
                o3 = __builtin_fmaf(w, __uint_as_float(v.y & 0xffff0000u), o3);
            }
            uint2 ov;
            ov.x = cvtpk(o0, o1);
            ov.y = cvtpk(o2, o3);
            *reinterpret_cast<uint2*>(&wr[t * CCH]) = ov;
        }
        __syncthreads();
        cur ^= 1;
    }

    // ---- final step m=11: f32 res, f32 out ----
    {
        const unsigned short* wp = wbase + (size_t)(NM - 1) * NTOK * 16;
        const char* rd = (const char*)&Vs[cur][0];
        #pragma unroll
        for (int j = 0; j < 4; ++j) {
            int t = j * 1024 + tid;
            int n = (bb << 12) + t;
            unsigned int t8 = (unsigned int)t * 8u;
            uint4 w0 = *reinterpret_cast<const uint4*>(wp + (size_t)t * 16);
            uint4 w1 = *reinterpret_cast<const uint4*>(wp + (size_t)t * 16 + 8);
            f32x4 rf = *reinterpret_cast<const f32x4*>(resF + (size_t)n * DIM + d0);
            float o0 = rf[0], o1 = rf[1], o2 = rf[2], o3 = rf[3];

            #pragma unroll
            for (int k = 0; k < NK; ++k) {
                const int off = (k == 0) ? 0 : (1 << (k - 1));
                unsigned int ww =
                    (k < 2) ? w0.x : (k < 4) ? w0.y : (k < 6) ? w0.z : (k < 8) ? w0.w :
                    (k < 10) ? w1.x : (k < 12) ? w1.y : w1.z;
                float w = (k & 1) ? __uint_as_float(ww & 0xffff0000u)
                                  : __uint_as_float(ww << 16);
                unsigned int a = (t8 + (unsigned int)off * 8u) & (unsigned int)(VBYTES - 1);
                uint2 v = *reinterpret_cast<const uint2*>(rd + a);
                o0 = __builtin_fmaf(w, __uint_as_float(v.x << 16),          o0);
                o1 = __builtin_fmaf(w, __uint_as_float(v.x & 0xffff0000u), o1);
                o2 = __builtin_fmaf(w, __uint_as_float(v.y << 16),          o2);
                o3 = __builtin_fmaf(w, __uint_as_float(v.y & 0xffff0000u), o3);
            }
            f32x4 o; o[0] = o0; o[1] = o1; o[2] = o2; o[3] = o3;
            *reinterpret_cast<f32x4*>(outF + (size_t)n * DIM + d0) = o;
        }
    }
}

// ---------------- launch ----------------
extern "C" void kernel_launch(void* const* d_in, const int* in_sizes, int n_in,
                              void* d_out, int out_size, void* d_ws, size_t ws_size,
                              hipStream_t stream) {
    const int*   data = (const int*)  d_in[0];
    const float* emb  = (const float*)d_in[2];
    const float* apc  = (const float*)d_in[3];
    const float* g_W1 = (const float*)d_in[4];
    const float* g_b1 = (const float*)d_in[5];
    const float* g_W2 = (const float*)d_in[6];
    const float* g_b2 = (const float*)d_in[7];
    const float* f_W1 = (const float*)d_in[8];
    const float* f_b1 = (const float*)d_in[9];
    const float* f_W2 = (const float*)d_in[10];
    const float* f_b2 = (const float*)d_in[11];
    float* out = (float*)d_out;

    char* ws = (char*)d_ws;
    size_t off = 0;
    auto alloc = [&](size_t bytes) {
        void* p = ws + off;
        off += (bytes + 255) & ~(size_t)255;
        return p;
    };
    unsigned short* xb    = (unsigned short*)alloc((size_t)NTOK * DIM * 2);
    unsigned short* wb1T  = (unsigned short*)alloc((size_t)NSEG * DIM * DIM * 2);
    unsigned short* wb2Tg = (unsigned short*)alloc((size_t)DIM * DIM * 2);
    unsigned short* wb2Tf = (unsigned short*)alloc((size_t)NM * 16 * DIM * 2);
    float*          resF  = (float*)alloc((size_t)NTOK * DIM * 4);
    unsigned short* resB  = (unsigned short*)alloc((size_t)NTOK * DIM * 2);
    unsigned short* Wallb = (unsigned short*)alloc((size_t)NM * NTOK * 16 * 2);
    (void)ws_size; (void)in_sizes; (void)n_in; (void)out_size;

    prep_kernel<<<EMB_BLOCKS + CONV_BLOCKS, 256, 0, stream>>>(
        data, emb, apc, xb, g_W1, g_W2, f_W1, f_W2, wb1T, wb2Tg, wb2Tf);

    dim3 grid(NTOK / 64, NSEG);
    mlp_kernel<<<grid, 256, 0, stream>>>(xb, wb1T, wb2Tg, wb2Tf,
                                         g_b1, g_b2, f_b1, f_b2, resF, resB, Wallb);

    // all 12 scan steps in one kernel: V channel-slices live in LDS
    scan_lds_kernel<<<128, 1024, 0, stream>>>(resB, resF, Wallb, out);
}

// Round 4
// 86.930 us; speedup vs baseline: 34.1486x; 1.1202x over previous
//
#include <hip/hip_runtime.h>
#include <hip/hip_bf16.h>

// ---------------- types ----------------
typedef __bf16 bf16x8 __attribute__((ext_vector_type(8)));
typedef float  f32x4  __attribute__((ext_vector_type(4)));
typedef unsigned short u16x8 __attribute__((ext_vector_type(8)));

#define NTOK 16384      // B*S
#define SEQ  4096
#define DIM  128
#define NSEG 13         // 1 g-segment + 12 f-segments
#define NM   12
#define NK   13

// round-to-nearest-even f32 -> bf16 bits
__device__ inline unsigned short f2bf(float f) {
    unsigned int u = __float_as_uint(f);
    unsigned int r = (u + 0x7FFFu + ((u >> 16) & 1u)) >> 16;
    return (unsigned short)r;
}
__device__ inline float bf2f(unsigned short h) {
    return __uint_as_float(((unsigned int)h) << 16);
}
// packed f32x2 -> bf16x2 (lo=a, hi=b), RNE (same as f2bf)
__device__ inline unsigned int cvtpk(float a, float b) {
    unsigned int r;
    asm("v_cvt_pk_bf16_f32 %0, %1, %2" : "=v"(r) : "v"(a), "v"(b));
    return r;
}

// 5-op gelu, CORRECT small-|u| form (leading correction is QUADRATIC):
//   gelu(u) = 0.5u + u^2*(c0 + u^2*c1 + u^4*c2),  c0=0.5*sqrt(2/pi), c1=-c0/6, c2=c0/40
__device__ inline float gelu_f(float u) {
    const float c0 = 0.3989422804f;
    const float c1 = -0.0664903801f;
    const float c2 = 0.0099735570f;
    float u2 = u * u;
    float p  = __builtin_fmaf(u2, c2, c1);
    p        = __builtin_fmaf(u2, p, c0);
    return __builtin_fmaf(u2, p, 0.5f * u);
}

// LDS XOR-swizzle: rows are 256B (128 u16). XOR byte bits [4:6] with row bits [8:10].
__device__ inline int swz(int u16idx) {
    int byte = u16idx << 1;
    byte ^= ((byte >> 8) & 7) << 4;
    return byte >> 1;
}

// ---------------- kernel 1: fused embed (x = emb[data]+apc -> bf16) + weight conv ----------------
#define EMB_BLOCKS 8192                         // 2 rows per 256-thread block
#define CONV_BLOCKS ((NSEG * DIM * DIM + 255) / 256)
__global__ __launch_bounds__(256) void prep_kernel(
    const int* __restrict__ data, const float* __restrict__ emb,
    const float* __restrict__ apc, unsigned short* __restrict__ xb,
    const float* __restrict__ g_W1, const float* __restrict__ g_W2,
    const float* __restrict__ f_W1, const float* __restrict__ f_W2,
    unsigned short* __restrict__ wb1T, unsigned short* __restrict__ wb2Tg,
    unsigned short* __restrict__ wb2Tf)
{
    int tid = threadIdx.x;
    if (blockIdx.x < EMB_BLOCKS) {
        int n = blockIdx.x * 2 + (tid >> 7);
        int d = tid & 127;
        int s = n & (SEQ - 1);
        int tok = data[n];
        float v = emb[(size_t)tok * DIM + d] + apc[s * DIM + d];
        xb[(size_t)n * DIM + d] = f2bf(v);
    } else {
        int i = (blockIdx.x - EMB_BLOCKS) * 256 + tid;
        if (i < NSEG * DIM * DIM) {
            int seg = i >> 14;
            int e = (i >> 7) & 127;
            int d = i & 127;
            float v = (seg == 0) ? g_W1[d * DIM + e]
                                 : f_W1[((seg - 1) * DIM + d) * DIM + e];
            wb1T[i] = f2bf(v);
        }
        if (i < DIM * DIM) {
            int c = i >> 7, e = i & 127;
            wb2Tg[i] = f2bf(g_W2[e * DIM + c]);
        }
        if (i < NM * 16 * DIM) {
            int m = i >> 11;
            int c = (i >> 7) & 15;
            int e = i & 127;
            float v = (c < NK) ? f_W2[(m * DIM + e) * NK + c] : 0.f;
            wb2Tf[i] = f2bf(v);
        }
    }
}

// ---------------- kernel 2: fused MLP — W in LDS (reused 32x), X direct from global ----------------
__global__ __launch_bounds__(256, 3) void mlp_kernel(
    const unsigned short* __restrict__ xb,
    const unsigned short* __restrict__ wb1T,
    const unsigned short* __restrict__ wb2Tg,
    const unsigned short* __restrict__ wb2Tf,
    const float* __restrict__ g_b1, const float* __restrict__ g_b2,
    const float* __restrict__ f_b1, const float* __restrict__ f_b2,
    float* __restrict__ resF, unsigned short* __restrict__ resB,
    unsigned short* __restrict__ Wallb)
{
    const int seg  = blockIdx.y;           // 0 => g ; 1..12 => f[seg-1]
    const int row0 = blockIdx.x * 64;
    const int tid  = threadIdx.x;
    const int wave = tid >> 6;             // 0..3
    const int lane = tid & 63;

    __shared__ __align__(16) unsigned short Hs[4][16 * DIM];  // 16 KB wave-private strips
    __shared__ __align__(16) unsigned short W1s[DIM * DIM];   // 32 KB
    __shared__ __align__(16) unsigned short W2fs[16 * DIM];   // 4 KB

    const int r16   = lane & 15;
    const int kgrp  = (lane >> 4) * 8;
    const int crow0 = (lane >> 4) << 2;    // strip-local C row base

    // biases into registers (overlaps staging)
    const float* b1p = (seg == 0) ? g_b1 : (f_b1 + (seg - 1) * DIM);
    float bias1[8];
    #pragma unroll
    for (int t = 0; t < 8; ++t) bias1[t] = b1p[t * 16 + r16];
    float bias2[8];
    float bias2f = 0.f;
    if (seg == 0) {
        #pragma unroll
        for (int t = 0; t < 8; ++t) bias2[t] = g_b2[t * 16 + r16];
    } else {
        bias2f = (r16 < NK) ? f_b2[(seg - 1) * NK + r16] : 0.f;
    }

    // stage W1T (128x128) swizzled
    {
        const int4* wg = reinterpret_cast<const int4*>(wb1T + (size_t)seg * DIM * DIM);
        #pragma unroll
        for (int i = 0; i < 8; ++i)
            *reinterpret_cast<int4*>(&W1s[swz((tid + i * 256) * 8)]) = wg[tid + i * 256];
    }
    // stage W2f (16x128) swizzled — f-segments only
    if (seg != 0) {
        const int4* wg = reinterpret_cast<const int4*>(wb2Tf + (size_t)(seg - 1) * 16 * DIM);
        *reinterpret_cast<int4*>(&W2fs[swz(tid * 8)]) = wg[tid];
    }
    __syncthreads();   // the ONLY barrier (waits on W staging only)

    // ---- layer 1: acc = X @ W1 ; A direct from global, B from LDS ----
    const unsigned short* xrow = xb + (size_t)(row0 + wave * 16 + r16) * DIM + kgrp;
    f32x4 acc[8];
    #pragma unroll
    for (int t = 0; t < 8; ++t) acc[t] = (f32x4){0.f, 0.f, 0.f, 0.f};
    #pragma unroll
    for (int kk = 0; kk < 4; ++kk) {
        bf16x8 a = *reinterpret_cast<const bf16x8*>(xrow + kk * 32);
        #pragma unroll
        for (int t = 0; t < 8; ++t) {
            bf16x8 b = *reinterpret_cast<const bf16x8*>(&W1s[swz((t * 16 + r16) * DIM + kk * 32 + kgrp)]);
            acc[t] = __builtin_amdgcn_mfma_f32_16x16x32_bf16(a, b, acc[t], 0, 0, 0);
        }
    }

    // ---- gelu -> H into this wave's own swizzled strip (cvt_pk pairs) ----
    unsigned short* hs = Hs[wave];
    #pragma unroll
    for (int t = 0; t < 8; ++t) {
        int col = t * 16 + r16;
        #pragma unroll
        for (int r = 0; r < 4; r += 2) {
            float g0 = gelu_f(acc[t][r]     + bias1[t]);
            float g1 = gelu_f(acc[t][r + 1] + bias1[t]);
            unsigned int pk = cvtpk(g0, g1);
            hs[swz((crow0 + r)     * DIM + col)] = (unsigned short)pk;
            hs[swz((crow0 + r + 1) * DIM + col)] = (unsigned short)(pk >> 16);
        }
    }

    // ---- layer 2 ----
    if (seg == 0) {
        f32x4 acc2[8];
        #pragma unroll
        for (int t = 0; t < 8; ++t) acc2[t] = (f32x4){0.f, 0.f, 0.f, 0.f};
        #pragma unroll
        for (int kk = 0; kk < 4; ++kk) {
            bf16x8 a = *reinterpret_cast<const bf16x8*>(&hs[swz(r16 * DIM + kk * 32 + kgrp)]);
            #pragma unroll
            for (int t = 0; t < 8; ++t) {
                bf16x8 b = *reinterpret_cast<const bf16x8*>(wb2Tg + (size_t)(t * 16 + r16) * DIM + kk * 32 + kgrp);
                acc2[t] = __builtin_amdgcn_mfma_f32_16x16x32_bf16(a, b, acc2[t], 0, 0, 0);
            }
        }
        #pragma unroll
        for (int t = 0; t < 8; ++t) {
            int col = t * 16 + r16;
            #pragma unroll
            for (int r = 0; r < 4; r += 2) {
                int grow = row0 + wave * 16 + crow0 + r;
                float v0 = acc2[t][r]     + bias2[t];
                float v1 = acc2[t][r + 1] + bias2[t];
                resF[(size_t)grow * DIM + col]       = v0;
                resF[(size_t)(grow + 1) * DIM + col] = v1;
                unsigned int pk = cvtpk(v0, v1);
                resB[(size_t)grow * DIM + col]       = (unsigned short)pk;
                resB[(size_t)(grow + 1) * DIM + col] = (unsigned short)(pk >> 16);
            }
        }
    } else {
        int m = seg - 1;
        f32x4 acc2 = (f32x4){0.f, 0.f, 0.f, 0.f};
        #pragma unroll
        for (int kk = 0; kk < 4; ++kk) {
            bf16x8 a = *reinterpret_cast<const bf16x8*>(&hs[swz(r16 * DIM + kk * 32 + kgrp)]);
            bf16x8 b = *reinterpret_cast<const bf16x8*>(&W2fs[swz(r16 * DIM + kk * 32 + kgrp)]);
            acc2 = __builtin_amdgcn_mfma_f32_16x16x32_bf16(a, b, acc2, 0, 0, 0);
        }
        #pragma unroll
        for (int r = 0; r < 4; r += 2) {
            int grow = row0 + wave * 16 + crow0 + r;
            unsigned int pk = cvtpk(acc2[r] + bias2f, acc2[r + 1] + bias2f);
            Wallb[((size_t)m * NTOK + grow) * 16 + r16]     = (unsigned short)pk;
            Wallb[((size_t)m * NTOK + grow + 1) * 16 + r16] = (unsigned short)(pk >> 16);
        }
    }
}

// ---------------- kernel 3: ALL 12 scan steps, V channel-slice in LDS, ring-padded ----------------
// Block = (batch, 2-channel chunk). V slice = (4096+2048) tok x 2 ch bf16 = 24 KB, double-
// buffered (48 KB). 256 blocks -> 1 per CU (full machine). The 2048-token pad duplicates
// tokens 0..2047 so every gather is ds_read_b32 with a COMPILE-TIME immediate offset
// (no wraparound address math in the inner loop). 1024 threads x 4 tokens each.
// Numerics bit-identical to the proven 12-launch path: bf16 V carry (RNE cvtpk), bf16 res
// steps 0..10, f32 resF + f32 out at step 11, same k-order FMA chain.
#define CCH 2
#define PADTOK (SEQ + 2048)             // 6144 tokens incl ring pad
__global__ __launch_bounds__(1024) void scan_lds_kernel(
    const unsigned short* __restrict__ resB,
    const float* __restrict__ resF,
    const unsigned short* __restrict__ Wallb,   // [NM][NTOK][16]
    float* __restrict__ outF)
{
    __shared__ unsigned int V32[2 * PADTOK];    // 1 u32 (2 bf16 ch) per token, 48 KB

    const int bb  = blockIdx.x >> 6;            // batch 0..3
    const int d0  = (blockIdx.x & 63) * CCH;    // channel chunk
    const int tid = threadIdx.x;                // 0..1023

    // ---- one-time: res regs (bf16 values) + seed V0 (with ring pad) ----
    float resLo[4], resHi[4];
    #pragma unroll
    for (int j = 0; j < 4; ++j) {
        int t = j * 1024 + tid;
        int n = (bb << 12) + t;
        unsigned int r = *reinterpret_cast<const unsigned int*>(resB + (size_t)n * DIM + d0);
        resLo[j] = __uint_as_float(r << 16);
        resHi[j] = __uint_as_float(r & 0xffff0000u);
        V32[t] = r;
        if (j < 2) V32[t + SEQ] = r;            // t < 2048 exactly when j < 2
    }
    __syncthreads();

    const unsigned short* wb0 = Wallb + (size_t)(bb << 12) * 16;
    unsigned int curbase = 0;

    // ---- steps 0..10: bf16 V carry in LDS ----
    #pragma unroll 1
    for (int m = 0; m < NM - 1; ++m) {
        const unsigned short* wp = wb0 + (size_t)m * NTOK * 16;
        const unsigned int nb = curbase ^ PADTOK;
        float oL[4], oH[4];
        #pragma unroll
        for (int j = 0; j < 4; ++j) {
            const int t = j * 1024 + tid;
            const uint4* wrow = reinterpret_cast<const uint4*>(wp + (size_t)t * 16);
            uint4 wa = wrow[0];
            uint4 wb = wrow[1];
            float o0 = resLo[j], o1 = resHi[j];
            const unsigned int* vb = &V32[curbase + t];
            #pragma unroll
            for (int k = 0; k < NK; ++k) {
                const int off = (k == 0) ? 0 : (1 << (k - 1));
                unsigned int ww =
                    (k < 2) ? wa.x : (k < 4) ? wa.y : (k < 6) ? wa.z : (k < 8) ? wa.w :
                    (k < 10) ? wb.x : (k < 12) ? wb.y : wb.z;
                float w = (k & 1) ? __uint_as_float(ww & 0xffff0000u)
                                  : __uint_as_float(ww << 16);
                unsigned int v = vb[off];       // ds_read_b32, imm offset
                o0 = __builtin_fmaf(w, __uint_as_float(v << 16),          o0);
                o1 = __builtin_fmaf(w, __uint_as_float(v & 0xffff0000u), o1);
            }
            oL[j] = o0; oH[j] = o1;
        }
        #pragma unroll
        for (int j = 0; j < 4; ++j) {
            int t = j * 1024 + tid;
            unsigned int pk = cvtpk(oL[j], oH[j]);
            V32[nb + t] = pk;
            if (j < 2) V32[nb + t + SEQ] = pk;
        }
        __syncthreads();
        curbase = nb;
    }

    // ---- final step m=11: f32 res, f32 out ----
    {
        const unsigned short* wp = wb0 + (size_t)(NM - 1) * NTOK * 16;
        #pragma unroll
        for (int j = 0; j < 4; ++j) {
            const int t = j * 1024 + tid;
            const int n = (bb << 12) + t;
            const uint4* wrow = reinterpret_cast<const uint4*>(wp + (size_t)t * 16);
            uint4 wa = wrow[0];
            uint4 wb = wrow[1];
            float2 rf = *reinterpret_cast<const float2*>(resF + (size_t)n * DIM + d0);
            float o0 = rf.x, o1 = rf.y;
            const unsigned int* vb = &V32[curbase + t];
            #pragma unroll
            for (int k = 0; k < NK; ++k) {
                const int off = (k == 0) ? 0 : (1 << (k - 1));
                unsigned int ww =
                    (k < 2) ? wa.x : (k < 4) ? wa.y : (k < 6) ? wa.z : (k < 8) ? wa.w :
                    (k < 10) ? wb.x : (k < 12) ? wb.y : wb.z;
                float w = (k & 1) ? __uint_as_float(ww & 0xffff0000u)
                                  : __uint_as_float(ww << 16);
                unsigned int v = vb[off];
                o0 = __builtin_fmaf(w, __uint_as_float(v << 16),          o0);
                o1 = __builtin_fmaf(w, __uint_as_float(v & 0xffff0000u), o1);
            }
            float2 o; o.x = o0; o.y = o1;
            *reinterpret_cast<float2*>(outF + (size_t)n * DIM + d0) = o;
        }
    }
}

// ---------------- launch ----------------
extern "C" void kernel_launch(void* const* d_in, const int* in_sizes, int n_in,
                              void* d_out, int out_size, void* d_ws, size_t ws_size,
                              hipStream_t stream) {
    const int*   data = (const int*)  d_in[0];
    const float* emb  = (const float*)d_in[2];
    const float* apc  = (const float*)d_in[3];
    const float* g_W1 = (const float*)d_in[4];
    const float* g_b1 = (const float*)d_in[5];
    const float* g_W2 = (const float*)d_in[6];
    const float* g_b2 = (const float*)d_in[7];
    const float* f_W1 = (const float*)d_in[8];
    const float* f_b1 = (const float*)d_in[9];
    const float* f_W2 = (const float*)d_in[10];
    const float* f_b2 = (const float*)d_in[11];
    float* out = (float*)d_out;

    char* ws = (char*)d_ws;
    size_t off = 0;
    auto alloc = [&](size_t bytes) {
        void* p = ws + off;
        off += (bytes + 255) & ~(size_t)255;
        return p;
    };
    unsigned short* xb    = (unsigned short*)alloc((size_t)NTOK * DIM * 2);
    unsigned short* wb1T  = (unsigned short*)alloc((size_t)NSEG * DIM * DIM * 2);
    unsigned short* wb2Tg = (unsigned short*)alloc((size_t)DIM * DIM * 2);
    unsigned short* wb2Tf = (unsigned short*)alloc((size_t)NM * 16 * DIM * 2);
    float*          resF  = (float*)alloc((size_t)NTOK * DIM * 4);
    unsigned short* resB  = (unsigned short*)alloc((size_t)NTOK * DIM * 2);
    unsigned short* Wallb = (unsigned short*)alloc((size_t)NM * NTOK * 16 * 2);
    (void)ws_size; (void)in_sizes; (void)n_in; (void)out_size;

    prep_kernel<<<EMB_BLOCKS + CONV_BLOCKS, 256, 0, stream>>>(
        data, emb, apc, xb, g_W1, g_W2, f_W1, f_W2, wb1T, wb2Tg, wb2Tf);

    dim3 grid(NTOK / 64, NSEG);
    mlp_kernel<<<grid, 256, 0, stream>>>(xb, wb1T, wb2Tg, wb2Tf,
                                         g_b1, g_b2, f_b1, f_b2, resF, resB, Wallb);

    // all 12 scan steps in one kernel: V channel-slices live in LDS (ring-padded)
    scan_lds_kernel<<<256, 1024, 0, stream>>>(resB, resF, Wallb, out);
}

// Round 5
// 77.344 us; speedup vs baseline: 38.3812x; 1.1239x over previous
//
#include <hip/hip_runtime.h>
#include <hip/hip_bf16.h>

// ---------------- types ----------------
typedef __bf16 bf16x8 __attribute__((ext_vector_type(8)));
typedef float  f32x4  __attribute__((ext_vector_type(4)));
typedef unsigned short u16x8 __attribute__((ext_vector_type(8)));

#define NTOK 16384      // B*S
#define SEQ  4096
#define DIM  128
#define NSEG 13         // 1 g-segment + 12 f-segments
#define NM   12
#define NK   13

// round-to-nearest-even f32 -> bf16 bits
__device__ inline unsigned short f2bf(float f) {
    unsigned int u = __float_as_uint(f);
    unsigned int r = (u + 0x7FFFu + ((u >> 16) & 1u)) >> 16;
    return (unsigned short)r;
}
__device__ inline float bf2f(unsigned short h) {
    return __uint_as_float(((unsigned int)h) << 16);
}
// packed f32x2 -> bf16x2 (lo=a, hi=b), RNE (same as f2bf)
__device__ inline unsigned int cvtpk(float a, float b) {
    unsigned int r;
    asm("v_cvt_pk_bf16_f32 %0, %1, %2" : "=v"(r) : "v"(a), "v"(b));
    return r;
}

// 5-op gelu, CORRECT small-|u| form (leading correction is QUADRATIC):
//   gelu(u) = 0.5u + u^2*(c0 + u^2*c1 + u^4*c2),  c0=0.5*sqrt(2/pi), c1=-c0/6, c2=c0/40
__device__ inline float gelu_f(float u) {
    const float c0 = 0.3989422804f;
    const float c1 = -0.0664903801f;
    const float c2 = 0.0099735570f;
    float u2 = u * u;
    float p  = __builtin_fmaf(u2, c2, c1);
    p        = __builtin_fmaf(u2, p, c0);
    return __builtin_fmaf(u2, p, 0.5f * u);
}

// LDS XOR-swizzle: rows are 256B (128 u16). XOR byte bits [4:6] with row bits [8:10].
__device__ inline int swz(int u16idx) {
    int byte = u16idx << 1;
    byte ^= ((byte >> 8) & 7) << 4;
    return byte >> 1;
}

// ---------------- kernel 1: fused embed (x = emb[data]+apc -> bf16) + weight conv ----------------
#define EMB_BLOCKS 8192                         // 2 rows per 256-thread block
#define CONV_BLOCKS ((NSEG * DIM * DIM + 255) / 256)
__global__ __launch_bounds__(256) void prep_kernel(
    const int* __restrict__ data, const float* __restrict__ emb,
    const float* __restrict__ apc, unsigned short* __restrict__ xb,
    const float* __restrict__ g_W1, const float* __restrict__ g_W2,
    const float* __restrict__ f_W1, const float* __restrict__ f_W2,
    unsigned short* __restrict__ wb1T, unsigned short* __restrict__ wb2Tg,
    unsigned short* __restrict__ wb2Tf)
{
    int tid = threadIdx.x;
    if (blockIdx.x < EMB_BLOCKS) {
        int n = blockIdx.x * 2 + (tid >> 7);
        int d = tid & 127;
        int s = n & (SEQ - 1);
        int tok = data[n];
        float v = emb[(size_t)tok * DIM + d] + apc[s * DIM + d];
        xb[(size_t)n * DIM + d] = f2bf(v);
    } else {
        int i = (blockIdx.x - EMB_BLOCKS) * 256 + tid;
        if (i < NSEG * DIM * DIM) {
            int seg = i >> 14;
            int e = (i >> 7) & 127;
            int d = i & 127;
            float v = (seg == 0) ? g_W1[d * DIM + e]
                                 : f_W1[((seg - 1) * DIM + d) * DIM + e];
            wb1T[i] = f2bf(v);
        }
        if (i < DIM * DIM) {
            int c = i >> 7, e = i & 127;
            wb2Tg[i] = f2bf(g_W2[e * DIM + c]);
        }
        if (i < NM * 16 * DIM) {
            int m = i >> 11;
            int c = (i >> 7) & 15;
            int e = i & 127;
            float v = (c < NK) ? f_W2[(m * DIM + e) * NK + c] : 0.f;
            wb2Tf[i] = f2bf(v);
        }
    }
}

// ---------------- kernel 2: fused MLP — W in LDS (reused 32x), X direct from global ----------------
__global__ __launch_bounds__(256, 3) void mlp_kernel(
    const unsigned short* __restrict__ xb,
    const unsigned short* __restrict__ wb1T,
    const unsigned short* __restrict__ wb2Tg,
    const unsigned short* __restrict__ wb2Tf,
    const float* __restrict__ g_b1, const float* __restrict__ g_b2,
    const float* __restrict__ f_b1, const float* __restrict__ f_b2,
    float* __restrict__ resF, unsigned short* __restrict__ resB,
    unsigned short* __restrict__ Wallb)
{
    const int seg  = blockIdx.y;           // 0 => g ; 1..12 => f[seg-1]
    const int row0 = blockIdx.x * 64;
    const int tid  = threadIdx.x;
    const int wave = tid >> 6;             // 0..3
    const int lane = tid & 63;

    __shared__ __align__(16) unsigned short Hs[4][16 * DIM];  // 16 KB wave-private strips
    __shared__ __align__(16) unsigned short W1s[DIM * DIM];   // 32 KB
    __shared__ __align__(16) unsigned short W2fs[16 * DIM];   // 4 KB

    const int r16   = lane & 15;
    const int kgrp  = (lane >> 4) * 8;
    const int crow0 = (lane >> 4) << 2;    // strip-local C row base

    // biases into registers (overlaps staging)
    const float* b1p = (seg == 0) ? g_b1 : (f_b1 + (seg - 1) * DIM);
    float bias1[8];
    #pragma unroll
    for (int t = 0; t < 8; ++t) bias1[t] = b1p[t * 16 + r16];
    float bias2[8];
    float bias2f = 0.f;
    if (seg == 0) {
        #pragma unroll
        for (int t = 0; t < 8; ++t) bias2[t] = g_b2[t * 16 + r16];
    } else {
        bias2f = (r16 < NK) ? f_b2[(seg - 1) * NK + r16] : 0.f;
    }

    // stage W1T (128x128) swizzled
    {
        const int4* wg = reinterpret_cast<const int4*>(wb1T + (size_t)seg * DIM * DIM);
        #pragma unroll
        for (int i = 0; i < 8; ++i)
            *reinterpret_cast<int4*>(&W1s[swz((tid + i * 256) * 8)]) = wg[tid + i * 256];
    }
    // stage W2f (16x128) swizzled — f-segments only
    if (seg != 0) {
        const int4* wg = reinterpret_cast<const int4*>(wb2Tf + (size_t)(seg - 1) * 16 * DIM);
        *reinterpret_cast<int4*>(&W2fs[swz(tid * 8)]) = wg[tid];
    }
    __syncthreads();   // the ONLY barrier (waits on W staging only)

    // ---- layer 1: acc = X @ W1 ; A direct from global, B from LDS ----
    const unsigned short* xrow = xb + (size_t)(row0 + wave * 16 + r16) * DIM + kgrp;
    f32x4 acc[8];
    #pragma unroll
    for (int t = 0; t < 8; ++t) acc[t] = (f32x4){0.f, 0.f, 0.f, 0.f};
    #pragma unroll
    for (int kk = 0; kk < 4; ++kk) {
        bf16x8 a = *reinterpret_cast<const bf16x8*>(xrow + kk * 32);
        #pragma unroll
        for (int t = 0; t < 8; ++t) {
            bf16x8 b = *reinterpret_cast<const bf16x8*>(&W1s[swz((t * 16 + r16) * DIM + kk * 32 + kgrp)]);
            acc[t] = __builtin_amdgcn_mfma_f32_16x16x32_bf16(a, b, acc[t], 0, 0, 0);
        }
    }

    // ---- gelu -> H into this wave's own swizzled strip (cvt_pk pairs) ----
    unsigned short* hs = Hs[wave];
    #pragma unroll
    for (int t = 0; t < 8; ++t) {
        int col = t * 16 + r16;
        #pragma unroll
        for (int r = 0; r < 4; r += 2) {
            float g0 = gelu_f(acc[t][r]     + bias1[t]);
            float g1 = gelu_f(acc[t][r + 1] + bias1[t]);
            unsigned int pk = cvtpk(g0, g1);
            hs[swz((crow0 + r)     * DIM + col)] = (unsigned short)pk;
            hs[swz((crow0 + r + 1) * DIM + col)] = (unsigned short)(pk >> 16);
        }
    }

    // ---- layer 2 ----
    if (seg == 0) {
        f32x4 acc2[8];
        #pragma unroll
        for (int t = 0; t < 8; ++t) acc2[t] = (f32x4){0.f, 0.f, 0.f, 0.f};
        #pragma unroll
        for (int kk = 0; kk < 4; ++kk) {
            bf16x8 a = *reinterpret_cast<const bf16x8*>(&hs[swz(r16 * DIM + kk * 32 + kgrp)]);
            #pragma unroll
            for (int t = 0; t < 8; ++t) {
                bf16x8 b = *reinterpret_cast<const bf16x8*>(wb2Tg + (size_t)(t * 16 + r16) * DIM + kk * 32 + kgrp);
                acc2[t] = __builtin_amdgcn_mfma_f32_16x16x32_bf16(a, b, acc2[t], 0, 0, 0);
            }
        }
        #pragma unroll
        for (int t = 0; t < 8; ++t) {
            int col = t * 16 + r16;
            #pragma unroll
            for (int r = 0; r < 4; r += 2) {
                int grow = row0 + wave * 16 + crow0 + r;
                float v0 = acc2[t][r]     + bias2[t];
                float v1 = acc2[t][r + 1] + bias2[t];
                resF[(size_t)grow * DIM + col]       = v0;
                resF[(size_t)(grow + 1) * DIM + col] = v1;
                unsigned int pk = cvtpk(v0, v1);
                resB[(size_t)grow * DIM + col]       = (unsigned short)pk;
                resB[(size_t)(grow + 1) * DIM + col] = (unsigned short)(pk >> 16);
            }
        }
    } else {
        int m = seg - 1;
        f32x4 acc2 = (f32x4){0.f, 0.f, 0.f, 0.f};
        #pragma unroll
        for (int kk = 0; kk < 4; ++kk) {
            bf16x8 a = *reinterpret_cast<const bf16x8*>(&hs[swz(r16 * DIM + kk * 32 + kgrp)]);
            bf16x8 b = *reinterpret_cast<const bf16x8*>(&W2fs[swz(r16 * DIM + kk * 32 + kgrp)]);
            acc2 = __builtin_amdgcn_mfma_f32_16x16x32_bf16(a, b, acc2, 0, 0, 0);
        }
        #pragma unroll
        for (int r = 0; r < 4; r += 2) {
            int grow = row0 + wave * 16 + crow0 + r;
            unsigned int pk = cvtpk(acc2[r] + bias2f, acc2[r + 1] + bias2f);
            Wallb[((size_t)m * NTOK + grow) * 16 + r16]     = (unsigned short)pk;
            Wallb[((size_t)m * NTOK + grow + 1) * 16 + r16] = (unsigned short)(pk >> 16);
        }
    }
}

// ---------------- kernel 3: ALL 12 scan steps, V channel-slice in LDS, ring-padded ----------------
// Block = (batch, 2-channel chunk), batch pinned to an XCD pair via bid&7 round-robin:
//   bb = (bid>>1)&3, chunk = ((bid>>3)<<1)|(bid&1)  ->  each XCD's L2 sees ONE batch's W.
// V slice = (4096+2048) tok x 2 ch bf16, double-buffered (48 KB). 256 blocks, 1/CU.
// W for step m+1 is PREFETCHED into registers during step m (hides L2/HBM latency);
// resF for the final step is loaded once at kernel start.
// Numerics bit-identical to the proven 12-launch path: bf16 V carry (RNE cvtpk), bf16 res
// steps 0..10, f32 resF + f32 out at step 11, same k-order FMA chain.
#define CCH 2
#define PADTOK (SEQ + 2048)             // 6144 tokens incl ring pad
__global__ __launch_bounds__(1024) void scan_lds_kernel(
    const unsigned short* __restrict__ resB,
    const float* __restrict__ resF,
    const unsigned short* __restrict__ Wallb,   // [NM][NTOK][16]
    float* __restrict__ outF)
{
    __shared__ unsigned int V32[2 * PADTOK];    // 1 u32 (2 bf16 ch) per token, 48 KB

    const int bid = (int)blockIdx.x;
    const int bb    = (bid >> 1) & 3;                 // batch -> XCD pair
    const int chunk = ((bid >> 3) << 1) | (bid & 1);  // 0..63
    const int d0  = chunk * CCH;
    const int tid = threadIdx.x;                      // 0..1023

    // ---- one-time: res regs (bf16 values) + seed V0 (with ring pad) ----
    float resLo[4], resHi[4];
    #pragma unroll
    for (int j = 0; j < 4; ++j) {
        int t = j * 1024 + tid;
        int n = (bb << 12) + t;
        unsigned int r = *reinterpret_cast<const unsigned int*>(resB + (size_t)n * DIM + d0);
        resLo[j] = __uint_as_float(r << 16);
        resHi[j] = __uint_as_float(r & 0xffff0000u);
        V32[t] = r;
        if (j < 2) V32[t + SEQ] = r;            // t < 2048 exactly when j < 2
    }

    // ---- hoisted load: f32 res for the final step (latency fully hidden) ----
    float2 rfv[4];
    #pragma unroll
    for (int j = 0; j < 4; ++j) {
        int n = (bb << 12) + j * 1024 + tid;
        rfv[j] = *reinterpret_cast<const float2*>(resF + (size_t)n * DIM + d0);
    }

    const unsigned short* wb0 = Wallb + (size_t)(bb << 12) * 16;

    // ---- preload W for step 0 ----
    uint4 wA[4][2];
    #pragma unroll
    for (int j = 0; j < 4; ++j) {
        const uint4* wrow = reinterpret_cast<const uint4*>(wb0 + (size_t)(j * 1024 + tid) * 16);
        wA[j][0] = wrow[0]; wA[j][1] = wrow[1];
    }
    __syncthreads();

    unsigned int curbase = 0;

    // ---- steps 0..10: bf16 V carry in LDS; W(m+1) prefetched during compute ----
    #pragma unroll 1
    for (int m = 0; m < NM - 1; ++m) {
        // issue next step's W loads first (consumed after compute -> latency hidden)
        uint4 wN[4][2];
        {
            const unsigned short* wpn = wb0 + (size_t)(m + 1) * NTOK * 16;
            #pragma unroll
            for (int j = 0; j < 4; ++j) {
                const uint4* wrow = reinterpret_cast<const uint4*>(wpn + (size_t)(j * 1024 + tid) * 16);
                wN[j][0] = wrow[0]; wN[j][1] = wrow[1];
            }
        }

        const unsigned int nb = curbase ^ PADTOK;
        float oL[4], oH[4];
        #pragma unroll
        for (int j = 0; j < 4; ++j) {
            const int t = j * 1024 + tid;
            uint4 wa = wA[j][0];
            uint4 wb = wA[j][1];
            float o0 = resLo[j], o1 = resHi[j];
            const unsigned int* vb = &V32[curbase + t];
            #pragma unroll
            for (int k = 0; k < NK; ++k) {
                const int off = (k == 0) ? 0 : (1 << (k - 1));
                unsigned int ww =
                    (k < 2) ? wa.x : (k < 4) ? wa.y : (k < 6) ? wa.z : (k < 8) ? wa.w :
                    (k < 10) ? wb.x : (k < 12) ? wb.y : wb.z;
                float w = (k & 1) ? __uint_as_float(ww & 0xffff0000u)
                                  : __uint_as_float(ww << 16);
                unsigned int v = vb[off];       // ds_read_b32, imm offset
                o0 = __builtin_fmaf(w, __uint_as_float(v << 16),          o0);
                o1 = __builtin_fmaf(w, __uint_as_float(v & 0xffff0000u), o1);
            }
            oL[j] = o0; oH[j] = o1;
        }
        #pragma unroll
        for (int j = 0; j < 4; ++j) {
            int t = j * 1024 + tid;
            unsigned int pk = cvtpk(oL[j], oH[j]);
            V32[nb + t] = pk;
            if (j < 2) V32[nb + t + SEQ] = pk;
        }
        // rotate prefetched W into place (vmcnt wait lands here, after compute)
        #pragma unroll
        for (int j = 0; j < 4; ++j) { wA[j][0] = wN[j][0]; wA[j][1] = wN[j][1]; }
        __syncthreads();
        curbase = nb;
    }

    // ---- final step m=11: f32 res (prefetched), f32 out; W already in wA ----
    {
        #pragma unroll
        for (int j = 0; j < 4; ++j) {
            const int t = j * 1024 + tid;
            const int n = (bb << 12) + t;
            uint4 wa = wA[j][0];
            uint4 wb = wA[j][1];
            float o0 = rfv[j].x, o1 = rfv[j].y;
            const unsigned int* vb = &V32[curbase + t];
            #pragma unroll
            for (int k = 0; k < NK; ++k) {
                const int off = (k == 0) ? 0 : (1 << (k - 1));
                unsigned int ww =
                    (k < 2) ? wa.x : (k < 4) ? wa.y : (k < 6) ? wa.z : (k < 8) ? wa.w :
                    (k < 10) ? wb.x : (k < 12) ? wb.y : wb.z;
                float w = (k & 1) ? __uint_as_float(ww & 0xffff0000u)
                                  : __uint_as_float(ww << 16);
                unsigned int v = vb[off];
                o0 = __builtin_fmaf(w, __uint_as_float(v << 16),          o0);
                o1 = __builtin_fmaf(w, __uint_as_float(v & 0xffff0000u), o1);
            }
            float2 o; o.x = o0; o.y = o1;
            *reinterpret_cast<float2*>(outF + (size_t)n * DIM + d0) = o;
        }
    }
}

// ---------------- launch ----------------
extern "C" void kernel_launch(void* const* d_in, const int* in_sizes, int n_in,
                              void* d_out, int out_size, void* d_ws, size_t ws_size,
                              hipStream_t stream) {
    const int*   data = (const int*)  d_in[0];
    const float* emb  = (const float*)d_in[2];
    const float* apc  = (const float*)d_in[3];
    const float* g_W1 = (const float*)d_in[4];
    const float* g_b1 = (const float*)d_in[5];
    const float* g_W2 = (const float*)d_in[6];
    const float* g_b2 = (const float*)d_in[7];
    const float* f_W1 = (const float*)d_in[8];
    const float* f_b1 = (const float*)d_in[9];
    const float* f_W2 = (const float*)d_in[10];
    const float* f_b2 = (const float*)d_in[11];
    float* out = (float*)d_out;

    char* ws = (char*)d_ws;
    size_t off = 0;
    auto alloc = [&](size_t bytes) {
        void* p = ws + off;
        off += (bytes + 255) & ~(size_t)255;
        return p;
    };
    unsigned short* xb    = (unsigned short*)alloc((size_t)NTOK * DIM * 2);
    unsigned short* wb1T  = (unsigned short*)alloc((size_t)NSEG * DIM * DIM * 2);
    unsigned short* wb2Tg = (unsigned short*)alloc((size_t)DIM * DIM * 2);
    unsigned short* wb2Tf = (unsigned short*)alloc((size_t)NM * 16 * DIM * 2);
    float*          resF  = (float*)alloc((size_t)NTOK * DIM * 4);
    unsigned short* resB  = (unsigned short*)alloc((size_t)NTOK * DIM * 2);
    unsigned short* Wallb = (unsigned short*)alloc((size_t)NM * NTOK * 16 * 2);
    (void)ws_size; (void)in_sizes; (void)n_in; (void)out_size;

    prep_kernel<<<EMB_BLOCKS + CONV_BLOCKS, 256, 0, stream>>>(
        data, emb, apc, xb, g_W1, g_W2, f_W1, f_W2, wb1T, wb2Tg, wb2Tf);

    dim3 grid(NTOK / 64, NSEG);
    mlp_kernel<<<grid, 256, 0, stream>>>(xb, wb1T, wb2Tg, wb2Tf,
                                         g_b1, g_b2, f_b1, f_b2, resF, resB, Wallb);

    // all 12 scan steps in one kernel: V channel-slices live in LDS (ring-padded),
    // W software-pipelined in registers, batch pinned to XCD pair
    scan_lds_kernel<<<256, 1024, 0, stream>>>(resB, resF, Wallb, out);
}